// Round 4
// baseline (372.876 us; speedup 1.0000x reference)
//
#include <hip/hip_runtime.h>
#include <math.h>

#define NB 4
#define NP 8192
#define KK 16
#define QPB 64
#define NPTS (NB * NP)

// ---- staged-filter geometry (round 4: all loop bodies verbatim-R0) ----
#define TSAMP 2048            // tau sample = candidates [0,2048)
#define BCH 1024              // filter chunk size
#define NBCH 8                // 8 chunks cover [0,8192)
#define CAP 30                // per-(query,chunk) index capacity
#define LSTRIDE 31            // u16 per (query,chunk): [0]=count, [1..30]=indices

// Fail-safe correctness (independent of tau's value):
//   S = {j : ref_d(j) <= tau}. If |S| >= 16 then d(16) <= tau, so the exact
//   top-16 is inside S and select's re-rank is exact. If |S| < 16 (or any
//   chunk count > CAP), select falls back to an exact full scan. Either way
//   the output equals the proven-R0 selection.

// comparator macros (exact: min/max introduce no rounding)
#define CSWAP_DESC(a, b) { float _lo = fminf(a, b); float _hi = fmaxf(a, b); a = _hi; b = _lo; }
#define CSWAP_ASC(a, b)  { float _lo = fminf(a, b); float _hi = fmaxf(a, b); a = _lo; b = _hi; }

// reference-rounded |p|^2 : (xx+yy)+zz
__device__ __forceinline__ float ref_sq(float x, float y, float z) {
  return __fadd_rn(__fadd_rn(__fmul_rn(x, x), __fmul_rn(y, y)), __fmul_rn(z, z));
}

// reference-rounded d2 = (sqq + sqc) - 2*dot, dot = (xx+yy)+zz
__device__ __forceinline__ float ref_d2q(float qx, float qy, float qz, float sqq,
                                         float4 c) {
  float dot = __fadd_rn(__fadd_rn(__fmul_rn(qx, c.x), __fmul_rn(qy, c.y)),
                        __fmul_rn(qz, c.z));
  float s = __fadd_rn(sqq, c.w);
  return __fmaf_rn(-2.0f, dot, s);
}

// batched top-16 update: 8 new distances d[0..7] vs sorted-asc bd[0..15]
__device__ __forceinline__ void topk_update(float bd[KK], float d[8]) {
  // Batcher odd-even mergesort-8, DESCENDING (19 comparators)
  CSWAP_DESC(d[0], d[1]) CSWAP_DESC(d[2], d[3]) CSWAP_DESC(d[4], d[5]) CSWAP_DESC(d[6], d[7])
  CSWAP_DESC(d[0], d[2]) CSWAP_DESC(d[1], d[3]) CSWAP_DESC(d[4], d[6]) CSWAP_DESC(d[5], d[7])
  CSWAP_DESC(d[1], d[2]) CSWAP_DESC(d[5], d[6])
  CSWAP_DESC(d[0], d[4]) CSWAP_DESC(d[1], d[5]) CSWAP_DESC(d[2], d[6]) CSWAP_DESC(d[3], d[7])
  CSWAP_DESC(d[2], d[4]) CSWAP_DESC(d[3], d[5])
  CSWAP_DESC(d[1], d[2]) CSWAP_DESC(d[3], d[4]) CSWAP_DESC(d[5], d[6])

  // [bd_asc(16), +inf x8, d_desc(8)] is bitonic; halver keeps 16 smallest
#pragma unroll
  for (int i = 0; i < 8; ++i) bd[8 + i] = fminf(bd[8 + i], d[i]);

  // bitonic merge-16 ascending cleanup (32 comparators)
#pragma unroll
  for (int i = 0; i < 8; ++i)  CSWAP_ASC(bd[i], bd[i + 8])
#pragma unroll
  for (int i = 0; i < 4; ++i)  CSWAP_ASC(bd[i], bd[i + 4])
#pragma unroll
  for (int i = 8; i < 12; ++i) CSWAP_ASC(bd[i], bd[i + 4])
#pragma unroll
  for (int g = 0; g < 4; ++g) {
    CSWAP_ASC(bd[4 * g + 0], bd[4 * g + 2]) CSWAP_ASC(bd[4 * g + 1], bd[4 * g + 3])
    CSWAP_ASC(bd[4 * g + 0], bd[4 * g + 1]) CSWAP_ASC(bd[4 * g + 2], bd[4 * g + 3])
  }
}

__global__ void prep_kernel(const float* __restrict__ x,
                            float4* __restrict__ cand) {
  int i = blockIdx.x * 256 + threadIdx.x;
  if (i < NPTS) {
    float px = x[3 * i + 0], py = x[3 * i + 1], pz = x[3 * i + 2];
    cand[i] = make_float4(px, py, pz, ref_sq(px, py, pz));
  }
}

// ---------------- kA: tau = exact 16th-smallest ref-dist over [0,2048) ------
// One 64-lane wave per query-group; R0-k1 pass-1 loop verbatim (bound 2048).
__global__ __launch_bounds__(64) void tau_stage_kernel(
    const float4* __restrict__ cand, float* __restrict__ tauArr) {
  const int lane  = threadIdx.x;
  const int group = blockIdx.x;              // 0..511
  const int batch = group >> 7;
  const int qbase = (group & 127) * QPB;
  const float4* __restrict__ Cb = cand + (size_t)batch * NP;

  const float4 q = Cb[qbase + lane];
  const float qx = q.x, qy = q.y, qz = q.z, sqq = q.w;

  float bd[KK];
#pragma unroll
  for (int t = 0; t < KK; ++t) bd[t] = 3.4e38f;

  for (int jj = 0; jj < TSAMP; jj += 8) {
    const float4* xp = Cb + jj;              // wave-uniform address
    float4 c[8];
#pragma unroll
    for (int u = 0; u < 8; ++u) c[u] = xp[u];
    float d[8];
#pragma unroll
    for (int u = 0; u < 8; ++u) d[u] = ref_d2q(qx, qy, qz, sqq, c[u]);
    topk_update(bd, d);
  }

  tauArr[batch * NP + qbase + lane] = bd[KK - 1];
}

// ---------------- kB: threshold filter (R0-k1 pass-2 verbatim shape) -------
// wave-task = (group, chunk). Predicated ascending-index append, u16 count.
__global__ __launch_bounds__(512) void filter_kernel(
    const float4* __restrict__ cand, const float* __restrict__ tauArr,
    unsigned short* __restrict__ lists) {
  const int tid   = threadIdx.x;
  const int lane  = tid & 63;
  const int w     = __builtin_amdgcn_readfirstlane(tid >> 6);
  const int group = blockIdx.x;              // 0..511
  const int batch = group >> 7;
  const int qbase = (group & 127) * QPB;
  const int ch    = w;                       // 0..7
  const int j0    = ch * BCH;
  const float4* __restrict__ Cb = cand + (size_t)batch * NP;

  const int qg = batch * NP + qbase + lane;
  const float tau = tauArr[qg];
  const float4 q = Cb[qbase + lane];
  const float qx = q.x, qy = q.y, qz = q.z, sqq = q.w;

  unsigned short* Lrow = lists + ((size_t)qg * NBCH + ch) * LSTRIDE;
  int cnt = 0;
  for (int jj = 0; jj < BCH; jj += 8) {
    const float4* xp = Cb + (j0 + jj);       // wave-uniform address
    float4 c[8];
#pragma unroll
    for (int u = 0; u < 8; ++u) c[u] = xp[u];
#pragma unroll
    for (int u = 0; u < 8; ++u) {
      float d = ref_d2q(qx, qy, qz, sqq, c[u]);
      if (d <= tau) {
        if (cnt < CAP) Lrow[1 + cnt] = (unsigned short)(j0 + jj + u);
        ++cnt;                               // count ALL survivors
      }
    }
  }
  Lrow[0] = (unsigned short)cnt;
}

// ---------------- kC: exact re-rank + covariance + eigen -------------------
// One query per thread. Pass 1: proven scalar insertion chain for T.
// Pass 2: R0-verbatim ascending-index threshold append. Any anomaly
// (chunk overflow, or fewer than 16 appended) => exact full-scan fallback.
__global__ __launch_bounds__(256) void select_eigen_kernel(
    const float4* __restrict__ cand, const unsigned short* __restrict__ lists,
    float* __restrict__ out) {
  __shared__ unsigned short s_mj[256][KK];   // 8 KB
  const int tid = threadIdx.x;
  const int g = blockIdx.x * 256 + tid;      // global query id
  const int batch = g >> 13;                 // / NP
  const float4* __restrict__ Cb = cand + (size_t)batch * NP;
  const unsigned short* Lq = lists + (size_t)g * NBCH * LSTRIDE;

  const float4 qq = Cb[g & (NP - 1)];
  const float q2x = qq.x, q2y = qq.y, q2z = qq.z, sq2 = qq.w;

  int cns[NBCH];
  bool fs = false;
#pragma unroll
  for (int ch = 0; ch < NBCH; ++ch) {
    cns[ch] = (int)Lq[ch * LSTRIDE];
    if (cns[ch] > CAP) fs = true;            // overflow -> full scan
  }

  if (!fs) {
    // pass 1: T = exact 16th-smallest over survivors (scalar insertion)
    float md[KK];
#pragma unroll
    for (int t = 0; t < KK; ++t) md[t] = 3.4e38f;
    for (int ch = 0; ch < NBCH; ++ch) {
      const unsigned short* L = Lq + ch * LSTRIDE + 1;
      const int cn = cns[ch];
      for (int e = 0; e < cn; ++e) {
        const float d = ref_d2q(q2x, q2y, q2z, sq2, Cb[(int)L[e]]);
        if (d < md[KK - 1]) {
#pragma unroll
          for (int t = KK - 1; t >= 1; --t)
            md[t] = fmaxf(md[t - 1], fminf(md[t], d));
          md[0] = fminf(md[0], d);
        }
      }
    }
    const float T = md[KK - 1];

    // pass 2: ascending-global-index threshold append (R0 semantics)
    int c16 = 0;
    for (int ch = 0; ch < NBCH; ++ch) {
      const unsigned short* L = Lq + ch * LSTRIDE + 1;
      const int cn = cns[ch];
      for (int e = 0; e < cn; ++e) {
        const int j = (int)L[e];
        const float d = ref_d2q(q2x, q2y, q2z, sq2, Cb[j]);
        if (d <= T && c16 < KK) { s_mj[tid][c16] = (unsigned short)j; ++c16; }
      }
    }
    if (c16 < KK) fs = true;                 // tau too small / any anomaly
  }

  if (fs) {
    // exact full-scan insertion with index tracking (verbatim-proven)
    float md[KK]; int mjr[KK];
#pragma unroll
    for (int t = 0; t < KK; ++t) { md[t] = 3.4e38f; mjr[t] = 0; }
    for (int j = 0; j < NP; ++j) {
      float d = ref_d2q(q2x, q2y, q2z, sq2, Cb[j]);
      if (d < md[KK - 1]) {
        bool c0 = d < md[0];
#pragma unroll
        for (int t = KK - 1; t >= 1; --t) {
          bool cl = d < md[t];
          bool cp = d < md[t - 1];
          float nv = fmaxf(md[t - 1], fminf(md[t], d));
          mjr[t] = cl ? (cp ? mjr[t - 1] : j) : mjr[t];
          md[t] = nv;
        }
        mjr[0] = c0 ? j : mjr[0];
        md[0] = fminf(md[0], d);
      }
    }
#pragma unroll
    for (int s = 0; s < KK; ++s) s_mj[tid][s] = (unsigned short)mjr[s];
  }

  // ---- covariance + eigen tail (verbatim-verified arithmetic)
  int mj[KK];
#pragma unroll
  for (int s = 0; s < KK; ++s) mj[s] = s_mj[tid][s];

  float sx = 0.f, sy = 0.f, sz = 0.f;
#pragma unroll
  for (int s = 0; s < KK; ++s) {
    float4 pp = Cb[mj[s]];
    sx = __fadd_rn(sx, pp.x);
    sy = __fadd_rn(sy, pp.y);
    sz = __fadd_rn(sz, pp.z);
  }
  const float k1 = 1.0f / KK;   // exact power of two
  const float mx = sx * k1, my = sy * k1, mz = sz * k1;

  float cxx = 0.f, cxy = 0.f, cxz = 0.f, cyy = 0.f, cyz = 0.f, czz = 0.f;
#pragma unroll
  for (int s = 0; s < KK; ++s) {
    float4 pp = Cb[mj[s]];
    float dx = __fsub_rn(pp.x, mx);
    float dy = __fsub_rn(pp.y, my);
    float dz = __fsub_rn(pp.z, mz);
    cxx = __fadd_rn(cxx, __fmul_rn(dx, dx));
    cxy = __fadd_rn(cxy, __fmul_rn(dx, dy));
    cxz = __fadd_rn(cxz, __fmul_rn(dx, dz));
    cyy = __fadd_rn(cyy, __fmul_rn(dy, dy));
    cyz = __fadd_rn(cyz, __fmul_rn(dy, dz));
    czz = __fadd_rn(czz, __fmul_rn(dz, dz));
  }

  double a   = (double)__fmul_rn(cxx, k1), b = (double)__fmul_rn(cyy, k1);
  double c2  = (double)__fmul_rn(czz, k1);
  double dxy = (double)__fmul_rn(cxy, k1), exz = (double)__fmul_rn(cxz, k1);
  double fyz = (double)__fmul_rn(cyz, k1);
  double qm = (a + b + c2) / 3.0;
  double p1 = dxy * dxy + exz * exz + fyz * fyz;
  double aa = a - qm, bb = b - qm, cc = c2 - qm;
  double p2 = aa * aa + bb * bb + cc * cc + 2.0 * p1;
  double ratio;
  if (p2 <= 0.0) {
    ratio = 1.0;
  } else {
    double p  = sqrt(p2 / 6.0);
    double ip = 1.0 / p;
    double b00 = aa * ip, b11 = bb * ip, b22 = cc * ip;
    double b01 = dxy * ip, b02 = exz * ip, b12 = fyz * ip;
    double detB = b00 * (b11 * b22 - b12 * b12)
                - b01 * (b01 * b22 - b12 * b02)
                + b02 * (b01 * b12 - b11 * b02);
    double r = 0.5 * detB;
    r = fmin(1.0, fmax(-1.0, r));
    double phi = acos(r) / 3.0;
    double e0 = qm + 2.0 * p * cos(phi);                      // largest
    double e2 = qm + 2.0 * p * cos(phi + 2.0943951023931954); // smallest
    double e1 = 3.0 * qm - e0 - e2;                           // middle
    ratio = e0 / e1;
  }
  out[g] = (float)ratio;
}

// ---------------- fallback: verbatim R4 single kernel (proven pass) ---------
__global__ __launch_bounds__(512, 4) void knn_eigen_fallback(
    const float4* __restrict__ cand, float* __restrict__ out) {
  __shared__ unsigned short s_j[8][QPB][18];

  const int tid   = threadIdx.x;
  const int lane  = tid & 63;
  const int w     = __builtin_amdgcn_readfirstlane(tid >> 6);
  const int batch = blockIdx.x >> 7;
  const int qbase = (blockIdx.x & 127) * QPB;
  const int FCH   = NP / 8;   // 1024

  const float4* __restrict__ Cb = cand + (size_t)batch * NP;

  const float4 q = Cb[qbase + lane];
  const float qx = q.x, qy = q.y, qz = q.z, sqq = q.w;

  float bd[KK];
#pragma unroll
  for (int t = 0; t < KK; ++t) bd[t] = 3.4e38f;

  const int j0 = w * FCH;
  for (int jj = 0; jj < FCH; jj += 8) {
    const float4* xp = Cb + (j0 + jj);
    float4 c[8];
#pragma unroll
    for (int u = 0; u < 8; ++u) c[u] = xp[u];
    float d[8];
#pragma unroll
    for (int u = 0; u < 8; ++u) d[u] = ref_d2q(qx, qy, qz, sqq, c[u]);
    topk_update(bd, d);
  }

  const float T = bd[KK - 1];
  int cnt = 0;
  for (int jj = 0; jj < FCH; jj += 8) {
    const float4* xp = Cb + (j0 + jj);
    float4 c[8];
#pragma unroll
    for (int u = 0; u < 8; ++u) c[u] = xp[u];
#pragma unroll
    for (int u = 0; u < 8; ++u) {
      float d = ref_d2q(qx, qy, qz, sqq, c[u]);
      if (d <= T && cnt < KK) {
        s_j[w][lane][cnt] = (unsigned short)(j0 + jj + u);
        cnt++;
      }
    }
  }
  __syncthreads();

  if (tid < QPB) {
    const float4 qq = Cb[qbase + tid];
    const float q2x = qq.x, q2y = qq.y, q2z = qq.z, sq2 = qq.w;
    float md[KK]; int mj[KK];
#pragma unroll
    for (int t = 0; t < KK; ++t) { md[t] = 3.4e38f; mj[t] = 0; }
    for (int cch = 0; cch < 8; ++cch) {
      const unsigned int* rowp = (const unsigned int*)&s_j[cch][tid][0];
#pragma unroll
      for (int sp = 0; sp < KK / 2; ++sp) {
        unsigned int pk = rowp[sp];
#pragma unroll
        for (int half = 0; half < 2; ++half) {
          int j = (half == 0) ? (int)(pk & 0xFFFFu) : (int)(pk >> 16);
          float d = ref_d2q(q2x, q2y, q2z, sq2, Cb[j]);
          if (d < md[KK - 1]) {
            bool c0 = d < md[0];
#pragma unroll
            for (int t = KK - 1; t >= 1; --t) {
              bool cl = d < md[t];
              bool cp = d < md[t - 1];
              float nv = fmaxf(md[t - 1], fminf(md[t], d));
              mj[t] = cl ? (cp ? mj[t - 1] : j) : mj[t];
              md[t] = nv;
            }
            mj[0] = c0 ? j : mj[0];
            md[0] = fminf(md[0], d);
          }
        }
      }
    }
    float sx = 0.f, sy = 0.f, sz = 0.f;
#pragma unroll
    for (int s = 0; s < KK; ++s) {
      float4 pp = Cb[mj[s]];
      sx = __fadd_rn(sx, pp.x);
      sy = __fadd_rn(sy, pp.y);
      sz = __fadd_rn(sz, pp.z);
    }
    const float k1 = 1.0f / KK;
    const float mx = sx * k1, my = sy * k1, mz = sz * k1;
    float cxx = 0.f, cxy = 0.f, cxz = 0.f, cyy = 0.f, cyz = 0.f, czz = 0.f;
#pragma unroll
    for (int s = 0; s < KK; ++s) {
      float4 pp = Cb[mj[s]];
      float dx = __fsub_rn(pp.x, mx);
      float dy = __fsub_rn(pp.y, my);
      float dz = __fsub_rn(pp.z, mz);
      cxx = __fadd_rn(cxx, __fmul_rn(dx, dx));
      cxy = __fadd_rn(cxy, __fmul_rn(dx, dy));
      cxz = __fadd_rn(cxz, __fmul_rn(dx, dz));
      cyy = __fadd_rn(cyy, __fmul_rn(dy, dy));
      cyz = __fadd_rn(cyz, __fmul_rn(dy, dz));
      czz = __fadd_rn(czz, __fmul_rn(dz, dz));
    }
    double a   = (double)__fmul_rn(cxx, k1), b = (double)__fmul_rn(cyy, k1);
    double c2  = (double)__fmul_rn(czz, k1);
    double dxy = (double)__fmul_rn(cxy, k1), exz = (double)__fmul_rn(cxz, k1);
    double fyz = (double)__fmul_rn(cyz, k1);
    double qm = (a + b + c2) / 3.0;
    double p1 = dxy * dxy + exz * exz + fyz * fyz;
    double aa = a - qm, bb = b - qm, cc = c2 - qm;
    double p2 = aa * aa + bb * bb + cc * cc + 2.0 * p1;
    double ratio;
    if (p2 <= 0.0) {
      ratio = 1.0;
    } else {
      double p  = sqrt(p2 / 6.0);
      double ip = 1.0 / p;
      double b00 = aa * ip, b11 = bb * ip, b22 = cc * ip;
      double b01 = dxy * ip, b02 = exz * ip, b12 = fyz * ip;
      double detB = b00 * (b11 * b22 - b12 * b12)
                  - b01 * (b01 * b22 - b12 * b02)
                  + b02 * (b01 * b12 - b11 * b02);
      double r = 0.5 * detB;
      r = fmin(1.0, fmax(-1.0, r));
      double phi = acos(r) / 3.0;
      double e0 = qm + 2.0 * p * cos(phi);
      double e2 = qm + 2.0 * p * cos(phi + 2.0943951023931954);
      double e1 = 3.0 * qm - e0 - e2;
      ratio = e0 / e1;
    }
    out[(size_t)batch * NP + qbase + tid] = (float)ratio;
  }
}

extern "C" void kernel_launch(void* const* d_in, const int* in_sizes, int n_in,
                              void* d_out, int out_size, void* d_ws, size_t ws_size,
                              hipStream_t stream) {
  const float* x = (const float*)d_in[0];
  float* out = (float*)d_out;
  float4* cand = (float4*)d_ws;                                   // 512 KB
  float* tauArr = (float*)((char*)d_ws + (size_t)NPTS * sizeof(float4)); // 128 KB
  unsigned short* lists =
      (unsigned short*)((char*)d_ws + (size_t)NPTS * sizeof(float4) +
                        (size_t)NPTS * sizeof(float));            // ~16.25 MB
  const size_t need = (size_t)NPTS * sizeof(float4) +
                      (size_t)NPTS * sizeof(float) +
                      (size_t)NPTS * NBCH * LSTRIDE * sizeof(unsigned short);
  // need = 16,908,288 B < proven-available 17,301,504 B

  prep_kernel<<<dim3(NPTS / 256), dim3(256), 0, stream>>>(x, cand);
  if (ws_size >= need) {
    tau_stage_kernel<<<dim3(512), dim3(64), 0, stream>>>(cand, tauArr);
    filter_kernel<<<dim3(512), dim3(512), 0, stream>>>(cand, tauArr, lists);
    select_eigen_kernel<<<dim3(NPTS / 256), dim3(256), 0, stream>>>(cand, lists, out);
  } else {
    knn_eigen_fallback<<<dim3(NPTS / QPB), dim3(512), 0, stream>>>(cand, out);
  }
}

// Round 5
// 259.893 us; speedup vs baseline: 1.4347x; 1.4347x over previous
//
#include <hip/hip_runtime.h>
#include <math.h>

#define NB 4
#define NP 8192
#define KK 16
#define QPB 64
#define NPTS (NB * NP)

// ---- staged-filter geometry ----
#define TSAMP 2048            // tau sample = candidates [0,2048)
#define TCH 512               // tau subchunk per wave
#define NTS 4                 // 4 waves per query-group
#define BCH 1024              // filter chunk size
#define NBCH 8                // 8 chunks cover [0,8192)
#define CAP 30                // per-(query,chunk) index capacity
#define LSTRIDE 31            // u16 per (query,chunk): [0]=count, [1..30]=indices

// Fail-safe correctness (independent of tau's value):
//   S = {j : ref_d(j) <= tau}. If |S| >= 16 then d(16) <= tau, so the exact
//   top-16 is inside S and select's re-rank is exact. If |S| < 16 (or any
//   chunk count > CAP), select falls back to an exact full scan. Either way
//   the output equals the proven-R0 selection. A tau bug can only cost time.

// comparator macros (exact: min/max introduce no rounding)
#define CSWAP_DESC(a, b) { float _lo = fminf(a, b); float _hi = fmaxf(a, b); a = _hi; b = _lo; }
#define CSWAP_ASC(a, b)  { float _lo = fminf(a, b); float _hi = fmaxf(a, b); a = _lo; b = _hi; }

// reference-rounded |p|^2 : (xx+yy)+zz
__device__ __forceinline__ float ref_sq(float x, float y, float z) {
  return __fadd_rn(__fadd_rn(__fmul_rn(x, x), __fmul_rn(y, y)), __fmul_rn(z, z));
}

// reference-rounded d2 = (sqq + sqc) - 2*dot, dot = (xx+yy)+zz
__device__ __forceinline__ float ref_d2q(float qx, float qy, float qz, float sqq,
                                         float4 c) {
  float dot = __fadd_rn(__fadd_rn(__fmul_rn(qx, c.x), __fmul_rn(qy, c.y)),
                        __fmul_rn(qz, c.z));
  float s = __fadd_rn(sqq, c.w);
  return __fmaf_rn(-2.0f, dot, s);
}

// batched top-16 update: 8 new distances d[0..7] vs sorted-asc bd[0..15]
__device__ __forceinline__ void topk_update(float bd[KK], float d[8]) {
  // Batcher odd-even mergesort-8, DESCENDING (19 comparators)
  CSWAP_DESC(d[0], d[1]) CSWAP_DESC(d[2], d[3]) CSWAP_DESC(d[4], d[5]) CSWAP_DESC(d[6], d[7])
  CSWAP_DESC(d[0], d[2]) CSWAP_DESC(d[1], d[3]) CSWAP_DESC(d[4], d[6]) CSWAP_DESC(d[5], d[7])
  CSWAP_DESC(d[1], d[2]) CSWAP_DESC(d[5], d[6])
  CSWAP_DESC(d[0], d[4]) CSWAP_DESC(d[1], d[5]) CSWAP_DESC(d[2], d[6]) CSWAP_DESC(d[3], d[7])
  CSWAP_DESC(d[2], d[4]) CSWAP_DESC(d[3], d[5])
  CSWAP_DESC(d[1], d[2]) CSWAP_DESC(d[3], d[4]) CSWAP_DESC(d[5], d[6])

  // [bd_asc(16), +inf x8, d_desc(8)] is bitonic; halver keeps 16 smallest
#pragma unroll
  for (int i = 0; i < 8; ++i) bd[8 + i] = fminf(bd[8 + i], d[i]);

  // bitonic merge-16 ascending cleanup (32 comparators)
#pragma unroll
  for (int i = 0; i < 8; ++i)  CSWAP_ASC(bd[i], bd[i + 8])
#pragma unroll
  for (int i = 0; i < 4; ++i)  CSWAP_ASC(bd[i], bd[i + 4])
#pragma unroll
  for (int i = 8; i < 12; ++i) CSWAP_ASC(bd[i], bd[i + 4])
#pragma unroll
  for (int g = 0; g < 4; ++g) {
    CSWAP_ASC(bd[4 * g + 0], bd[4 * g + 2]) CSWAP_ASC(bd[4 * g + 1], bd[4 * g + 3])
    CSWAP_ASC(bd[4 * g + 0], bd[4 * g + 1]) CSWAP_ASC(bd[4 * g + 2], bd[4 * g + 3])
  }
}

__global__ void prep_kernel(const float* __restrict__ x,
                            float4* __restrict__ cand) {
  int i = blockIdx.x * 256 + threadIdx.x;
  if (i < NPTS) {
    float px = x[3 * i + 0], py = x[3 * i + 1], pz = x[3 * i + 2];
    cand[i] = make_float4(px, py, pz, ref_sq(px, py, pz));
  }
}

// ---------------- kA: tau = 16th-smallest ref-dist over [0,2048) ------------
// 8 waves/block = 2 groups x 4 subchunk-waves; sub-lists merged via LDS.
// 2048 waves total (was 512 in R4 -> latency-bound at 2 waves/CU).
// tau errors are harmless (fail-safe) -- this stage only affects speed.
__global__ __launch_bounds__(512) void tau_stage_kernel(
    const float4* __restrict__ cand, float* __restrict__ tauArr) {
  __shared__ float s_t[2][NTS][64][KK];      // 32 KB
  const int tid   = threadIdx.x;
  const int lane  = tid & 63;
  const int w     = __builtin_amdgcn_readfirstlane(tid >> 6);
  const int gl    = w >> 2;                  // group-in-block 0/1
  const int sub   = w & 3;                   // 0..3
  const int group = blockIdx.x * 2 + gl;     // 0..511
  const int batch = group >> 7;
  const int qbase = (group & 127) * QPB;
  const float4* __restrict__ Cb = cand + (size_t)batch * NP;

  const float4 q = Cb[qbase + lane];
  const float qx = q.x, qy = q.y, qz = q.z, sqq = q.w;

  float bd[KK];
#pragma unroll
  for (int t = 0; t < KK; ++t) bd[t] = 3.4e38f;

  const int j0 = sub * TCH;
  for (int jj = 0; jj < TCH; jj += 8) {
    const float4* xp = Cb + (j0 + jj);       // wave-uniform address
    float4 c[8];
#pragma unroll
    for (int u = 0; u < 8; ++u) c[u] = xp[u];
    float d[8];
#pragma unroll
    for (int u = 0; u < 8; ++u) d[u] = ref_d2q(qx, qy, qz, sqq, c[u]);
    topk_update(bd, d);
  }

#pragma unroll
  for (int t = 0; t < KK; ++t) s_t[gl][sub][lane][t] = bd[t];
  __syncthreads();

  if (sub == 0) {                            // wave-uniform branch
    float md[KK];
#pragma unroll
    for (int t = 0; t < KK; ++t) md[t] = s_t[gl][0][lane][t];  // sorted asc
#pragma unroll
    for (int s2 = 1; s2 < NTS; ++s2) {
      float d[KK];
#pragma unroll
      for (int t = 0; t < KK; ++t) d[t] = s_t[gl][s2][lane][t];
      topk_update(md, &d[0]);
      topk_update(md, &d[8]);
    }
    tauArr[batch * NP + qbase + lane] = md[KK - 1];
  }
}

// ---------------- kB: threshold filter (R4 verbatim, proven) ---------------
__global__ __launch_bounds__(512) void filter_kernel(
    const float4* __restrict__ cand, const float* __restrict__ tauArr,
    unsigned short* __restrict__ lists) {
  const int tid   = threadIdx.x;
  const int lane  = tid & 63;
  const int w     = __builtin_amdgcn_readfirstlane(tid >> 6);
  const int group = blockIdx.x;              // 0..511
  const int batch = group >> 7;
  const int qbase = (group & 127) * QPB;
  const int ch    = w;                       // 0..7
  const int j0    = ch * BCH;
  const float4* __restrict__ Cb = cand + (size_t)batch * NP;

  const int qg = batch * NP + qbase + lane;
  const float tau = tauArr[qg];
  const float4 q = Cb[qbase + lane];
  const float qx = q.x, qy = q.y, qz = q.z, sqq = q.w;

  unsigned short* Lrow = lists + ((size_t)qg * NBCH + ch) * LSTRIDE;
  int cnt = 0;
  for (int jj = 0; jj < BCH; jj += 8) {
    const float4* xp = Cb + (j0 + jj);       // wave-uniform address
    float4 c[8];
#pragma unroll
    for (int u = 0; u < 8; ++u) c[u] = xp[u];
#pragma unroll
    for (int u = 0; u < 8; ++u) {
      float d = ref_d2q(qx, qy, qz, sqq, c[u]);
      if (d <= tau) {
        if (cnt < CAP) Lrow[1 + cnt] = (unsigned short)(j0 + jj + u);
        ++cnt;                               // count ALL survivors
      }
    }
  }
  Lrow[0] = (unsigned short)cnt;
}

// ---------------- kC: exact re-rank + covariance + eigen -------------------
// One query per thread. Same semantics as proven R4 kernel; only change is
// batching the gathers 8-wide into registers before the serial chains
// (padding with +inf = no-op in the insertion network; appends ok-guarded).
__global__ __launch_bounds__(256) void select_eigen_kernel(
    const float4* __restrict__ cand, const unsigned short* __restrict__ lists,
    float* __restrict__ out) {
  __shared__ unsigned short s_mj[256][KK];   // 8 KB
  const int tid = threadIdx.x;
  const int g = blockIdx.x * 256 + tid;      // global query id
  const int batch = g >> 13;                 // / NP
  const float4* __restrict__ Cb = cand + (size_t)batch * NP;
  const unsigned short* Lq = lists + (size_t)g * NBCH * LSTRIDE;

  const float4 qq = Cb[g & (NP - 1)];
  const float q2x = qq.x, q2y = qq.y, q2z = qq.z, sq2 = qq.w;

  int cns[NBCH];
  bool fs = false;
#pragma unroll
  for (int ch = 0; ch < NBCH; ++ch) {
    cns[ch] = (int)Lq[ch * LSTRIDE];
    if (cns[ch] > CAP) fs = true;            // overflow -> full scan
  }

  if (!fs) {
    // pass 1: T = exact 16th-smallest over survivors (batched-load insertion)
    float md[KK];
#pragma unroll
    for (int t = 0; t < KK; ++t) md[t] = 3.4e38f;
    for (int ch = 0; ch < NBCH; ++ch) {
      const unsigned short* L = Lq + ch * LSTRIDE + 1;
      const int cn = cns[ch];
      for (int e = 0; e < cn; e += 8) {
        float dv[8];
#pragma unroll
        for (int u = 0; u < 8; ++u) {
          const bool ok = (e + u) < cn;
          const int j = ok ? (int)L[e + u] : 0;    // all 8 gathers in flight
          const float dd = ref_d2q(q2x, q2y, q2z, sq2, Cb[j]);
          dv[u] = ok ? dd : 3.4e38f;               // +inf pad: insertion no-op
        }
#pragma unroll
        for (int u = 0; u < 8; ++u) {
          const float d = dv[u];
          if (d < md[KK - 1]) {
#pragma unroll
            for (int t = KK - 1; t >= 1; --t)
              md[t] = fmaxf(md[t - 1], fminf(md[t], d));
            md[0] = fminf(md[0], d);
          }
        }
      }
    }
    const float T = md[KK - 1];

    // pass 2: ascending-global-index threshold append (R0 semantics),
    // loads batched 8-wide, append serial and ok-guarded.
    int c16 = 0;
    for (int ch = 0; ch < NBCH; ++ch) {
      const unsigned short* L = Lq + ch * LSTRIDE + 1;
      const int cn = cns[ch];
      for (int e = 0; e < cn; e += 8) {
        int jv[8];
        float dv[8];
#pragma unroll
        for (int u = 0; u < 8; ++u) {
          const bool ok = (e + u) < cn;
          jv[u] = ok ? (int)L[e + u] : 0;
          const float dd = ref_d2q(q2x, q2y, q2z, sq2, Cb[jv[u]]);
          dv[u] = ok ? dd : 3.4e38f;
        }
#pragma unroll
        for (int u = 0; u < 8; ++u) {
          const bool ok = (e + u) < cn;
          if (ok && dv[u] <= T && c16 < KK) {
            s_mj[tid][c16] = (unsigned short)jv[u];
            ++c16;
          }
        }
      }
    }
    if (c16 < KK) fs = true;                 // tau too small / any anomaly
  }

  if (fs) {
    // exact full-scan insertion with index tracking (verbatim-proven)
    float md[KK]; int mjr[KK];
#pragma unroll
    for (int t = 0; t < KK; ++t) { md[t] = 3.4e38f; mjr[t] = 0; }
    for (int j = 0; j < NP; ++j) {
      float d = ref_d2q(q2x, q2y, q2z, sq2, Cb[j]);
      if (d < md[KK - 1]) {
        bool c0 = d < md[0];
#pragma unroll
        for (int t = KK - 1; t >= 1; --t) {
          bool cl = d < md[t];
          bool cp = d < md[t - 1];
          float nv = fmaxf(md[t - 1], fminf(md[t], d));
          mjr[t] = cl ? (cp ? mjr[t - 1] : j) : mjr[t];
          md[t] = nv;
        }
        mjr[0] = c0 ? j : mjr[0];
        md[0] = fminf(md[0], d);
      }
    }
#pragma unroll
    for (int s = 0; s < KK; ++s) s_mj[tid][s] = (unsigned short)mjr[s];
  }

  // ---- covariance + eigen tail (verbatim-verified arithmetic)
  int mj[KK];
#pragma unroll
  for (int s = 0; s < KK; ++s) mj[s] = s_mj[tid][s];

  float sx = 0.f, sy = 0.f, sz = 0.f;
#pragma unroll
  for (int s = 0; s < KK; ++s) {
    float4 pp = Cb[mj[s]];
    sx = __fadd_rn(sx, pp.x);
    sy = __fadd_rn(sy, pp.y);
    sz = __fadd_rn(sz, pp.z);
  }
  const float k1 = 1.0f / KK;   // exact power of two
  const float mx = sx * k1, my = sy * k1, mz = sz * k1;

  float cxx = 0.f, cxy = 0.f, cxz = 0.f, cyy = 0.f, cyz = 0.f, czz = 0.f;
#pragma unroll
  for (int s = 0; s < KK; ++s) {
    float4 pp = Cb[mj[s]];
    float dx = __fsub_rn(pp.x, mx);
    float dy = __fsub_rn(pp.y, my);
    float dz = __fsub_rn(pp.z, mz);
    cxx = __fadd_rn(cxx, __fmul_rn(dx, dx));
    cxy = __fadd_rn(cxy, __fmul_rn(dx, dy));
    cxz = __fadd_rn(cxz, __fmul_rn(dx, dz));
    cyy = __fadd_rn(cyy, __fmul_rn(dy, dy));
    cyz = __fadd_rn(cyz, __fmul_rn(dy, dz));
    czz = __fadd_rn(czz, __fmul_rn(dz, dz));
  }

  double a   = (double)__fmul_rn(cxx, k1), b = (double)__fmul_rn(cyy, k1);
  double c2  = (double)__fmul_rn(czz, k1);
  double dxy = (double)__fmul_rn(cxy, k1), exz = (double)__fmul_rn(cxz, k1);
  double fyz = (double)__fmul_rn(cyz, k1);
  double qm = (a + b + c2) / 3.0;
  double p1 = dxy * dxy + exz * exz + fyz * fyz;
  double aa = a - qm, bb = b - qm, cc = c2 - qm;
  double p2 = aa * aa + bb * bb + cc * cc + 2.0 * p1;
  double ratio;
  if (p2 <= 0.0) {
    ratio = 1.0;
  } else {
    double p  = sqrt(p2 / 6.0);
    double ip = 1.0 / p;
    double b00 = aa * ip, b11 = bb * ip, b22 = cc * ip;
    double b01 = dxy * ip, b02 = exz * ip, b12 = fyz * ip;
    double detB = b00 * (b11 * b22 - b12 * b12)
                - b01 * (b01 * b22 - b12 * b02)
                + b02 * (b01 * b12 - b11 * b02);
    double r = 0.5 * detB;
    r = fmin(1.0, fmax(-1.0, r));
    double phi = acos(r) / 3.0;
    double e0 = qm + 2.0 * p * cos(phi);                      // largest
    double e2 = qm + 2.0 * p * cos(phi + 2.0943951023931954); // smallest
    double e1 = 3.0 * qm - e0 - e2;                           // middle
    ratio = e0 / e1;
  }
  out[g] = (float)ratio;
}

// ---------------- fallback: verbatim single kernel (proven pass) ------------
__global__ __launch_bounds__(512, 4) void knn_eigen_fallback(
    const float4* __restrict__ cand, float* __restrict__ out) {
  __shared__ unsigned short s_j[8][QPB][18];

  const int tid   = threadIdx.x;
  const int lane  = tid & 63;
  const int w     = __builtin_amdgcn_readfirstlane(tid >> 6);
  const int batch = blockIdx.x >> 7;
  const int qbase = (blockIdx.x & 127) * QPB;
  const int FCH   = NP / 8;   // 1024

  const float4* __restrict__ Cb = cand + (size_t)batch * NP;

  const float4 q = Cb[qbase + lane];
  const float qx = q.x, qy = q.y, qz = q.z, sqq = q.w;

  float bd[KK];
#pragma unroll
  for (int t = 0; t < KK; ++t) bd[t] = 3.4e38f;

  const int j0 = w * FCH;
  for (int jj = 0; jj < FCH; jj += 8) {
    const float4* xp = Cb + (j0 + jj);
    float4 c[8];
#pragma unroll
    for (int u = 0; u < 8; ++u) c[u] = xp[u];
    float d[8];
#pragma unroll
    for (int u = 0; u < 8; ++u) d[u] = ref_d2q(qx, qy, qz, sqq, c[u]);
    topk_update(bd, d);
  }

  const float T = bd[KK - 1];
  int cnt = 0;
  for (int jj = 0; jj < FCH; jj += 8) {
    const float4* xp = Cb + (j0 + jj);
    float4 c[8];
#pragma unroll
    for (int u = 0; u < 8; ++u) c[u] = xp[u];
#pragma unroll
    for (int u = 0; u < 8; ++u) {
      float d = ref_d2q(qx, qy, qz, sqq, c[u]);
      if (d <= T && cnt < KK) {
        s_j[w][lane][cnt] = (unsigned short)(j0 + jj + u);
        cnt++;
      }
    }
  }
  __syncthreads();

  if (tid < QPB) {
    const float4 qq = Cb[qbase + tid];
    const float q2x = qq.x, q2y = qq.y, q2z = qq.z, sq2 = qq.w;
    float md[KK]; int mj[KK];
#pragma unroll
    for (int t = 0; t < KK; ++t) { md[t] = 3.4e38f; mj[t] = 0; }
    for (int cch = 0; cch < 8; ++cch) {
      const unsigned int* rowp = (const unsigned int*)&s_j[cch][tid][0];
#pragma unroll
      for (int sp = 0; sp < KK / 2; ++sp) {
        unsigned int pk = rowp[sp];
#pragma unroll
        for (int half = 0; half < 2; ++half) {
          int j = (half == 0) ? (int)(pk & 0xFFFFu) : (int)(pk >> 16);
          float d = ref_d2q(q2x, q2y, q2z, sq2, Cb[j]);
          if (d < md[KK - 1]) {
            bool c0 = d < md[0];
#pragma unroll
            for (int t = KK - 1; t >= 1; --t) {
              bool cl = d < md[t];
              bool cp = d < md[t - 1];
              float nv = fmaxf(md[t - 1], fminf(md[t], d));
              mj[t] = cl ? (cp ? mj[t - 1] : j) : mj[t];
              md[t] = nv;
            }
            mj[0] = c0 ? j : mj[0];
            md[0] = fminf(md[0], d);
          }
        }
      }
    }
    float sx = 0.f, sy = 0.f, sz = 0.f;
#pragma unroll
    for (int s = 0; s < KK; ++s) {
      float4 pp = Cb[mj[s]];
      sx = __fadd_rn(sx, pp.x);
      sy = __fadd_rn(sy, pp.y);
      sz = __fadd_rn(sz, pp.z);
    }
    const float k1 = 1.0f / KK;
    const float mx = sx * k1, my = sy * k1, mz = sz * k1;
    float cxx = 0.f, cxy = 0.f, cxz = 0.f, cyy = 0.f, cyz = 0.f, czz = 0.f;
#pragma unroll
    for (int s = 0; s < KK; ++s) {
      float4 pp = Cb[mj[s]];
      float dx = __fsub_rn(pp.x, mx);
      float dy = __fsub_rn(pp.y, my);
      float dz = __fsub_rn(pp.z, mz);
      cxx = __fadd_rn(cxx, __fmul_rn(dx, dx));
      cxy = __fadd_rn(cxy, __fmul_rn(dx, dy));
      cxz = __fadd_rn(cxz, __fmul_rn(dx, dz));
      cyy = __fadd_rn(cyy, __fmul_rn(dy, dy));
      cyz = __fadd_rn(cyz, __fmul_rn(dy, dz));
      czz = __fadd_rn(czz, __fmul_rn(dz, dz));
    }
    double a   = (double)__fmul_rn(cxx, k1), b = (double)__fmul_rn(cyy, k1);
    double c2  = (double)__fmul_rn(czz, k1);
    double dxy = (double)__fmul_rn(cxy, k1), exz = (double)__fmul_rn(cxz, k1);
    double fyz = (double)__fmul_rn(cyz, k1);
    double qm = (a + b + c2) / 3.0;
    double p1 = dxy * dxy + exz * exz + fyz * fyz;
    double aa = a - qm, bb = b - qm, cc = c2 - qm;
    double p2 = aa * aa + bb * bb + cc * cc + 2.0 * p1;
    double ratio;
    if (p2 <= 0.0) {
      ratio = 1.0;
    } else {
      double p  = sqrt(p2 / 6.0);
      double ip = 1.0 / p;
      double b00 = aa * ip, b11 = bb * ip, b22 = cc * ip;
      double b01 = dxy * ip, b02 = exz * ip, b12 = fyz * ip;
      double detB = b00 * (b11 * b22 - b12 * b12)
                  - b01 * (b01 * b22 - b12 * b02)
                  + b02 * (b01 * b12 - b11 * b02);
      double r = 0.5 * detB;
      r = fmin(1.0, fmax(-1.0, r));
      double phi = acos(r) / 3.0;
      double e0 = qm + 2.0 * p * cos(phi);
      double e2 = qm + 2.0 * p * cos(phi + 2.0943951023931954);
      double e1 = 3.0 * qm - e0 - e2;
      ratio = e0 / e1;
    }
    out[(size_t)batch * NP + qbase + tid] = (float)ratio;
  }
}

extern "C" void kernel_launch(void* const* d_in, const int* in_sizes, int n_in,
                              void* d_out, int out_size, void* d_ws, size_t ws_size,
                              hipStream_t stream) {
  const float* x = (const float*)d_in[0];
  float* out = (float*)d_out;
  float4* cand = (float4*)d_ws;                                   // 512 KB
  float* tauArr = (float*)((char*)d_ws + (size_t)NPTS * sizeof(float4)); // 128 KB
  unsigned short* lists =
      (unsigned short*)((char*)d_ws + (size_t)NPTS * sizeof(float4) +
                        (size_t)NPTS * sizeof(float));            // ~16.25 MB
  const size_t need = (size_t)NPTS * sizeof(float4) +
                      (size_t)NPTS * sizeof(float) +
                      (size_t)NPTS * NBCH * LSTRIDE * sizeof(unsigned short);
  // need = 16,908,288 B < proven-available 17,301,504 B

  prep_kernel<<<dim3(NPTS / 256), dim3(256), 0, stream>>>(x, cand);
  if (ws_size >= need) {
    tau_stage_kernel<<<dim3(256), dim3(512), 0, stream>>>(cand, tauArr);
    filter_kernel<<<dim3(512), dim3(512), 0, stream>>>(cand, tauArr, lists);
    select_eigen_kernel<<<dim3(NPTS / 256), dim3(256), 0, stream>>>(cand, lists, out);
  } else {
    knn_eigen_fallback<<<dim3(NPTS / QPB), dim3(512), 0, stream>>>(cand, out);
  }
}